// Round 6
// baseline (407.494 us; speedup 1.0000x reference)
//
#include <hip/hip_runtime.h>
#include <math.h>

#define NN   4096
#define DIM  256
#define NE   131072
#define NH   4
#define DH   64
#define F1D  128
#define NG   16
#define AD   32

typedef unsigned short u16;
typedef unsigned int   u32;
typedef __attribute__((ext_vector_type(8))) short short8b;
typedef __attribute__((ext_vector_type(4))) float f32x4;

enum { EPI_BIAS = 0, EPI_BNELU = 1, EPI_BIAS_ELU = 2, EPI_BIAS_RES = 3 };

__device__ inline u16 f2bf(float x) {
    u32 u = __float_as_uint(x);
    u += 0x7fffu + ((u >> 16) & 1u);
    return (u16)(u >> 16);
}
__device__ inline float bf2f(u16 h) {
    return __uint_as_float(((u32)h) << 16);
}
__device__ inline u32 packbf(float a, float b) {
    return (u32)f2bf(a) | ((u32)f2bf(b) << 16);
}

// ---------------- CSR build ----------------
__global__ void csr_count(const int* __restrict__ dst, int* __restrict__ cnt) {
    int e = blockIdx.x * 256 + threadIdx.x;
    atomicAdd(&cnt[dst[e]], 1);
}

__global__ void csr_scan(const int* __restrict__ cnt, int* __restrict__ off) {
    int lane = threadIdx.x;
    int base = lane * (NN / 64);
    int s = 0;
    for (int i = 0; i < NN / 64; ++i) s += cnt[base + i];
    int acc = s;
    #pragma unroll
    for (int o = 1; o < 64; o <<= 1) {
        int t = __shfl_up(acc, o);
        if (lane >= o) acc += t;
    }
    int run = acc - s;
    for (int i = 0; i < NN / 64; ++i) { off[base + i] = run; run += cnt[base + i]; }
    if (lane == 63) off[NN] = run;
}

__global__ void csr_fill(const int* __restrict__ dst, const int* __restrict__ src,
                         const float* __restrict__ eattr, const int* __restrict__ off,
                         int* __restrict__ cur, int* __restrict__ esrc,
                         float* __restrict__ ewt) {
    int e = blockIdx.x * 256 + threadIdx.x;
    int d = dst[e];
    int pos = off[d] + atomicAdd(&cur[d], 1);
    esrc[pos] = src[e];
    ewt[pos]  = eattr[e];
}

// ---------------- neighbor aggregation: 1 wave per node -------------------
template<bool LAST>
__global__ __launch_bounds__(256) void agg_kernel(
    const float* __restrict__ x, const int* __restrict__ esrc,
    const float* __restrict__ ewt, const int* __restrict__ off,
    float* __restrict__ agg)
{
    const int node = blockIdx.x * 4 + (threadIdx.x >> 6);
    const int lane = threadIdx.x & 63;
    const int d4 = lane * 4;
    int j = off[node];
    const int j1 = off[node + 1];
    float4 acc = make_float4(0.f, 0.f, 0.f, 0.f);
    for (; j + 4 <= j1; j += 4) {
        const int s0 = esrc[j], s1 = esrc[j + 1], s2 = esrc[j + 2], s3 = esrc[j + 3];
        const float4 x0 = *(const float4*)&x[(size_t)s0 * DIM + d4];
        const float4 x1 = *(const float4*)&x[(size_t)s1 * DIM + d4];
        const float4 x2 = *(const float4*)&x[(size_t)s2 * DIM + d4];
        const float4 x3 = *(const float4*)&x[(size_t)s3 * DIM + d4];
        const float w0 = LAST ? ewt[j]     : 1.f;
        const float w1 = LAST ? ewt[j + 1] : 1.f;
        const float w2 = LAST ? ewt[j + 2] : 1.f;
        const float w3 = LAST ? ewt[j + 3] : 1.f;
        acc.x = fmaf(x0.x, w0, acc.x); acc.y = fmaf(x0.y, w0, acc.y);
        acc.z = fmaf(x0.z, w0, acc.z); acc.w = fmaf(x0.w, w0, acc.w);
        acc.x = fmaf(x1.x, w1, acc.x); acc.y = fmaf(x1.y, w1, acc.y);
        acc.z = fmaf(x1.z, w1, acc.z); acc.w = fmaf(x1.w, w1, acc.w);
        acc.x = fmaf(x2.x, w2, acc.x); acc.y = fmaf(x2.y, w2, acc.y);
        acc.z = fmaf(x2.z, w2, acc.z); acc.w = fmaf(x2.w, w2, acc.w);
        acc.x = fmaf(x3.x, w3, acc.x); acc.y = fmaf(x3.y, w3, acc.y);
        acc.z = fmaf(x3.z, w3, acc.z); acc.w = fmaf(x3.w, w3, acc.w);
    }
    for (; j < j1; ++j) {
        const int s = esrc[j];
        const float w = LAST ? ewt[j] : 1.f;
        const float4 xv = *(const float4*)&x[(size_t)s * DIM + d4];
        acc.x = fmaf(xv.x, w, acc.x); acc.y = fmaf(xv.y, w, acc.y);
        acc.z = fmaf(xv.z, w, acc.z); acc.w = fmaf(xv.w, w, acc.w);
    }
    *(float4*)&agg[(size_t)node * DIM + d4] = acc;
}

// ---------------- split-K fp32 GEMM: partials, no epilogue ---------------
// grid (M/64, NN/64, NSK). Chunk z covers k-tiles [z*chunkKT, (z+1)*chunkKT)
// of the (DUAL ? 2K : K)-long K range. Partial -> pbuf[z][NN][M].
template<bool DUAL>
__global__ __launch_bounds__(256) void gemm_splitk(
    const float* __restrict__ A0, const float* __restrict__ B0,
    const float* __restrict__ A1, const float* __restrict__ B1,
    float* __restrict__ pbuf, int K, int M, int chunkKT)
{
    __shared__ float As[16][68];
    __shared__ float Bs[16][64];

    const int tid  = threadIdx.x;
    const int row0 = blockIdx.y * 64;
    const int col0 = blockIdx.x * 64;
    const int z    = blockIdx.z;
    const int kStart = z * chunkKT * 16;
    const int kEnd   = kStart + chunkKT * 16;

    const int ty = tid >> 4;
    const int tx = tid & 15;
    const int lrow = tid >> 2;
    const int lk4  = (tid & 3) * 4;
    const int bk   = tid >> 4;
    const int bc4  = (tid & 15) * 4;

    float acc[4][4] = {};
    float4 av, bv;
    {
        const bool ip1 = DUAL && (kStart >= K);
        const float* A = ip1 ? A1 : A0;
        const float* B = ip1 ? B1 : B0;
        const int kb = ip1 ? (kStart - K) : kStart;
        av = *(const float4*)&A[(size_t)(row0 + lrow) * K + kb + lk4];
        bv = *(const float4*)&B[(size_t)(kb + bk) * M + col0 + bc4];
    }
    for (int k0 = kStart; k0 < kEnd; k0 += 16) {
        __syncthreads();
        As[lk4 + 0][lrow] = av.x;
        As[lk4 + 1][lrow] = av.y;
        As[lk4 + 2][lrow] = av.z;
        As[lk4 + 3][lrow] = av.w;
        *(float4*)&Bs[bk][bc4] = bv;
        if (k0 + 16 < kEnd) {
            const int kn = k0 + 16;
            const bool ph1 = DUAL && (kn >= K);
            const float* A = ph1 ? A1 : A0;
            const float* B = ph1 ? B1 : B0;
            const int kb = ph1 ? (kn - K) : kn;
            av = *(const float4*)&A[(size_t)(row0 + lrow) * K + kb + lk4];
            bv = *(const float4*)&B[(size_t)(kb + bk) * M + col0 + bc4];
        }
        __syncthreads();
        #pragma unroll
        for (int kk = 0; kk < 16; ++kk) {
            float4 a = *(const float4*)&As[kk][ty * 4];
            float4 b = *(const float4*)&Bs[kk][tx * 4];
            acc[0][0] = fmaf(a.x, b.x, acc[0][0]);
            acc[0][1] = fmaf(a.x, b.y, acc[0][1]);
            acc[0][2] = fmaf(a.x, b.z, acc[0][2]);
            acc[0][3] = fmaf(a.x, b.w, acc[0][3]);
            acc[1][0] = fmaf(a.y, b.x, acc[1][0]);
            acc[1][1] = fmaf(a.y, b.y, acc[1][1]);
            acc[1][2] = fmaf(a.y, b.z, acc[1][2]);
            acc[1][3] = fmaf(a.y, b.w, acc[1][3]);
            acc[2][0] = fmaf(a.z, b.x, acc[2][0]);
            acc[2][1] = fmaf(a.z, b.y, acc[2][1]);
            acc[2][2] = fmaf(a.z, b.z, acc[2][2]);
            acc[2][3] = fmaf(a.z, b.w, acc[2][3]);
            acc[3][0] = fmaf(a.w, b.x, acc[3][0]);
            acc[3][1] = fmaf(a.w, b.y, acc[3][1]);
            acc[3][2] = fmaf(a.w, b.z, acc[3][2]);
            acc[3][3] = fmaf(a.w, b.w, acc[3][3]);
        }
    }
    float* pb = pbuf + (size_t)z * NN * M;
    #pragma unroll
    for (int i = 0; i < 4; ++i) {
        const int r = row0 + ty * 4 + i;
        *(float4*)&pb[(size_t)r * M + col0 + tx * 4] =
            make_float4(acc[i][0], acc[i][1], acc[i][2], acc[i][3]);
    }
}

// reduce NSK partials + bias + epilogue
template<int EPI, int NSK>
__global__ __launch_bounds__(256) void reduce_epi(
    const float* __restrict__ pbuf, const float* __restrict__ bias,
    const float* __restrict__ gamma, const float* __restrict__ beta,
    const float* __restrict__ bnmean, const float* __restrict__ bnvar,
    const float* __restrict__ resid, float* __restrict__ out, int M)
{
    const int gid = blockIdx.x * 256 + threadIdx.x;
    const int mq  = M / 4;
    const int row = gid / mq;
    const int c4  = (gid % mq) * 4;
    const size_t base = (size_t)row * M + c4;
    float4 s = *(const float4*)&pbuf[base];
    #pragma unroll
    for (int z = 1; z < NSK; ++z) {
        const float4 t = *(const float4*)&pbuf[(size_t)z * NN * M + base];
        s.x += t.x; s.y += t.y; s.z += t.z; s.w += t.w;
    }
    float v[4] = {s.x, s.y, s.z, s.w};
    #pragma unroll
    for (int j = 0; j < 4; ++j) {
        const int c = c4 + j;
        float t = v[j] + bias[c];
        if (EPI == EPI_BNELU) {
            t = gamma[c] * (t - bnmean[c]) * rsqrtf(bnvar[c] + 1e-5f) + beta[c];
            t = t > 0.f ? t : expm1f(t);
        } else if (EPI == EPI_BIAS_ELU) {
            t = t > 0.f ? t : expm1f(t);
        } else if (EPI == EPI_BIAS_RES) {
            t += resid[base + j];
        }
        v[j] = t;
    }
    *(float4*)&out[base] = make_float4(v[0], v[1], v[2], v[3]);
}

// ---------------- fused QKV GEMM (single launch, bf16 hi/lo epilogue) -----
__global__ __launch_bounds__(256) void gemm_qkv(
    const float* __restrict__ A0, const float* __restrict__ B0,
    const float* __restrict__ bias,
    u16* __restrict__ qh_o, u16* __restrict__ ql_o,
    u16* __restrict__ kh_o, u16* __restrict__ kl_o,
    u16* __restrict__ vt_o)
{
    __shared__ float As[16][68];
    __shared__ float Bs[16][64];
    const int K = DIM, M = DIM;

    const int tid  = threadIdx.x;
    const int row0 = blockIdx.y * 64;
    const int c0raw = blockIdx.x * 64;
    const int mat  = c0raw >> 8;
    const int col0 = c0raw & 255;
    const float* Bp = B0 + (size_t)mat * K * M;
    const float* biasp = bias + mat * M;

    const int ty = tid >> 4;
    const int tx = tid & 15;
    const int lrow = tid >> 2;
    const int lk4  = (tid & 3) * 4;
    const int bk   = tid >> 4;
    const int bc4  = (tid & 15) * 4;

    float acc[4][4] = {};
    float4 av, bv;
    av = *(const float4*)&A0[(size_t)(row0 + lrow) * K + lk4];
    bv = *(const float4*)&Bp[(size_t)bk * M + col0 + bc4];
    for (int k0 = 0; k0 < K; k0 += 16) {
        __syncthreads();
        As[lk4 + 0][lrow] = av.x;
        As[lk4 + 1][lrow] = av.y;
        As[lk4 + 2][lrow] = av.z;
        As[lk4 + 3][lrow] = av.w;
        *(float4*)&Bs[bk][bc4] = bv;
        if (k0 + 16 < K) {
            const int kb = k0 + 16;
            av = *(const float4*)&A0[(size_t)(row0 + lrow) * K + kb + lk4];
            bv = *(const float4*)&Bp[(size_t)(kb + bk) * M + col0 + bc4];
        }
        __syncthreads();
        #pragma unroll
        for (int kk = 0; kk < 16; ++kk) {
            float4 a = *(const float4*)&As[kk][ty * 4];
            float4 b = *(const float4*)&Bs[kk][tx * 4];
            acc[0][0] = fmaf(a.x, b.x, acc[0][0]);
            acc[0][1] = fmaf(a.x, b.y, acc[0][1]);
            acc[0][2] = fmaf(a.x, b.z, acc[0][2]);
            acc[0][3] = fmaf(a.x, b.w, acc[0][3]);
            acc[1][0] = fmaf(a.y, b.x, acc[1][0]);
            acc[1][1] = fmaf(a.y, b.y, acc[1][1]);
            acc[1][2] = fmaf(a.y, b.z, acc[1][2]);
            acc[1][3] = fmaf(a.y, b.w, acc[1][3]);
            acc[2][0] = fmaf(a.z, b.x, acc[2][0]);
            acc[2][1] = fmaf(a.z, b.y, acc[2][1]);
            acc[2][2] = fmaf(a.z, b.z, acc[2][2]);
            acc[2][3] = fmaf(a.z, b.w, acc[2][3]);
            acc[3][0] = fmaf(a.w, b.x, acc[3][0]);
            acc[3][1] = fmaf(a.w, b.y, acc[3][1]);
            acc[3][2] = fmaf(a.w, b.z, acc[3][2]);
            acc[3][3] = fmaf(a.w, b.w, acc[3][3]);
        }
    }
    if (mat < 2) {
        const float s = (mat == 0) ? 0.125f : 1.0f;
        u16* hi = (mat == 0) ? qh_o : kh_o;
        u16* lo = (mat == 0) ? ql_o : kl_o;
        #pragma unroll
        for (int i = 0; i < 4; ++i) {
            const int r = row0 + ty * 4 + i;
            const int c = col0 + tx * 4;
            u32 wh[2], wl[2];
            #pragma unroll
            for (int g = 0; g < 2; ++g) {
                float v0 = (acc[i][g * 2]     + biasp[c + g * 2])     * s;
                float v1 = (acc[i][g * 2 + 1] + biasp[c + g * 2 + 1]) * s;
                u16 h0 = f2bf(v0), h1 = f2bf(v1);
                float l0 = v0 - bf2f(h0), l1 = v1 - bf2f(h1);
                wh[g] = (u32)h0 | ((u32)h1 << 16);
                wl[g] = packbf(l0, l1);
            }
            *(uint2*)&hi[(size_t)r * DIM + c] = make_uint2(wh[0], wh[1]);
            *(uint2*)&lo[(size_t)r * DIM + c] = make_uint2(wl[0], wl[1]);
        }
    } else {
        #pragma unroll
        for (int j = 0; j < 4; ++j) {
            const int c = col0 + tx * 4 + j;
            const int r = row0 + ty * 4;
            float v0 = acc[0][j] + biasp[c];
            float v1 = acc[1][j] + biasp[c];
            float v2 = acc[2][j] + biasp[c];
            float v3 = acc[3][j] + biasp[c];
            *(uint2*)&vt_o[(size_t)c * NN + r] =
                make_uint2(packbf(v0, v1), packbf(v2, v3));
        }
    }
}

// ---------------- MFMA flash attention -----------------------------------
// 64x64 tiles; QK^T fp32-emulated via bf16 hi/lo (4 mfma passes); PV bf16.
// P stored [q][k] (stride 72 u16) so PV B-fragments are single ds_read_b128.
// LDS 38144 B, NSPLIT=4 -> grid 1024 = 4 blocks/CU = 16 waves/CU.
#define QB 64
#define KB 64
#define NSPLIT 4
#define NKT (NN / KB)
#define KP 72

__global__ __launch_bounds__(256, 4) void attn_kernel(
    const u16* __restrict__ qhi, const u16* __restrict__ qlo,
    const u16* __restrict__ khi, const u16* __restrict__ klo,
    const u16* __restrict__ vT,
    float* __restrict__ op0, float* __restrict__ op1,
    float* __restrict__ op2, float* __restrict__ op3,
    float* __restrict__ mpart, float* __restrict__ lpart)
{
    __shared__ u16 lds[19072];            // 38144 B
    u16* Kh = lds;                        // [64][72]
    u16* Kl = lds + 4608;
    u16* Vt = lds + 9216;                 // [key][d] per-head (transposed V^T rows)
    u16* Pb = lds + 13824;                // [q][72]  P bf16
    u16* Qh = lds;                        // overlay: init phase only
    u16* Ql = lds + 4608;                 // overlay: init phase only
    float* fls = (float*)(lds + 18432);   // 320 floats
    float* mh0 = fls;
    float* mh1 = fls + 64;
    float* lh0 = fls + 128;
    float* lh1 = fls + 192;
    float* frow = fls + 256;

    const int tid = threadIdx.x;
    const int h   = blockIdx.y;
    const int q0  = blockIdx.x * QB;
    const int sp  = blockIdx.z;
    const int kt0 = (sp * NKT) / NSPLIT;
    const int kt1 = ((sp + 1) * NKT) / NSPLIT;

    const int w   = tid >> 6;
    const int l   = tid & 63;
    const int l15 = l & 15, h4 = l >> 4;
    const int qh  = w & 1, kh = w >> 1;

    const int lrow = tid & 63, lseg = tid >> 6;
    const int gq = h * DH + lseg * 16;

    {   // stage Q (once, into overlay region)
        const u16* s0 = qhi + (size_t)(q0 + lrow) * DIM + gq;
        const u16* s1 = qlo + (size_t)(q0 + lrow) * DIM + gq;
        uint4 a = ((const uint4*)s0)[0], b = ((const uint4*)s0)[1];
        uint4 c = ((const uint4*)s1)[0], d = ((const uint4*)s1)[1];
        *(uint4*)&Qh[lrow * KP + lseg * 16]     = a;
        *(uint4*)&Qh[lrow * KP + lseg * 16 + 8] = b;
        *(uint4*)&Ql[lrow * KP + lseg * 16]     = c;
        *(uint4*)&Ql[lrow * KP + lseg * 16 + 8] = d;
    }
    uint4 ska, skb, sla, slb, sva, svb;
    {
        const int key0 = kt0 * KB;
        const u16* s0 = khi + (size_t)(key0 + lrow) * DIM + gq;
        const u16* s1 = klo + (size_t)(key0 + lrow) * DIM + gq;
        const u16* s2 = vT + (size_t)(h * DH + lrow) * NN + key0 + lseg * 16;
        ska = ((const uint4*)s0)[0]; skb = ((const uint4*)s0)[1];
        sla = ((const uint4*)s1)[0]; slb = ((const uint4*)s1)[1];
        sva = ((const uint4*)s2)[0]; svb = ((const uint4*)s2)[1];
    }
    __syncthreads();                              // Q staged

    short8b qf[2][2][2];
    #pragma unroll
    for (int qb = 0; qb < 2; ++qb)
        #pragma unroll
        for (int kc = 0; kc < 2; ++kc) {
            const int r = qh * 32 + qb * 16 + l15;
            const int dc = kc * 32 + h4 * 8;
            qf[qb][kc][0] = *(const short8b*)&Qh[r * KP + dc];
            qf[qb][kc][1] = *(const short8b*)&Ql[r * KP + dc];
        }
    __syncthreads();                              // hoist done; overlay safe

    const f32x4 z4 = {0.f, 0.f, 0.f, 0.f};
    f32x4 oacc[2][2] = {{z4, z4}, {z4, z4}};
    float m_run[2][4], l_run[2][4];
    #pragma unroll
    for (int qb = 0; qb < 2; ++qb)
        #pragma unroll
        for (int i = 0; i < 4; ++i) { m_run[qb][i] = -3.0e38f; l_run[qb][i] = 0.f; }

    for (int kt = kt0; kt < kt1; ++kt) {
        *(uint4*)&Kh[lrow * KP + lseg * 16]     = ska;
        *(uint4*)&Kh[lrow * KP + lseg * 16 + 8] = skb;
        *(uint4*)&Kl[lrow * KP + lseg * 16]     = sla;
        *(uint4*)&Kl[lrow * KP + lseg * 16 + 8] = slb;
        *(uint4*)&Vt[lrow * KP + lseg * 16]     = sva;
        *(uint4*)&Vt[lrow * KP + lseg * 16 + 8] = svb;
        __syncthreads();                          // tile staged

        // ---- S = Q K^T (4-pass hi/lo) ----
        f32x4 sc[2][2] = {{z4, z4}, {z4, z4}};
        __builtin_amdgcn_s_setprio(1);
        #pragma unroll
        for (int kc = 0; kc < 2; ++kc) {
            short8b kfh[2], kfl[2];
            #pragma unroll
            for (int kcb = 0; kcb < 2; ++kcb) {
                const int r = kh * 32 + kcb * 16 + l15;
                const int dc = kc * 32 + h4 * 8;
                kfh[kcb] = *(const short8b*)&Kh[r * KP + dc];
                kfl[kcb] = *(const short8b*)&Kl[r * KP + dc];
            }
            #pragma unroll
            for (int qb = 0; qb < 2; ++qb)
                #pragma unroll
                for (int kcb = 0; kcb < 2; ++kcb) {
                    sc[qb][kcb] = __builtin_amdgcn_mfma_f32_16x16x32_bf16(
                        qf[qb][kc][0], kfh[kcb], sc[qb][kcb], 0, 0, 0);
                    sc[qb][kcb] = __builtin_amdgcn_mfma_f32_16x16x32_bf16(
                        qf[qb][kc][0], kfl[kcb], sc[qb][kcb], 0, 0, 0);
                    sc[qb][kcb] = __builtin_amdgcn_mfma_f32_16x16x32_bf16(
                        qf[qb][kc][1], kfh[kcb], sc[qb][kcb], 0, 0, 0);
                    sc[qb][kcb] = __builtin_amdgcn_mfma_f32_16x16x32_bf16(
                        qf[qb][kc][1], kfl[kcb], sc[qb][kcb], 0, 0, 0);
                }
        }
        __builtin_amdgcn_s_setprio(0);
        // prefetch next tile while softmax runs
        if (kt + 1 < kt1) {
            const int key0 = (kt + 1) * KB;
            const u16* s0 = khi + (size_t)(key0 + lrow) * DIM + gq;
            const u16* s1 = klo + (size_t)(key0 + lrow) * DIM + gq;
            const u16* s2 = vT + (size_t)(h * DH + lrow) * NN + key0 + lseg * 16;
            ska = ((const uint4*)s0)[0]; skb = ((const uint4*)s0)[1];
            sla = ((const uint4*)s1)[0]; slb = ((const uint4*)s1)[1];
            sva = ((const uint4*)s2)[0]; svb = ((const uint4*)s2)[1];
        }
        // ---- softmax part 1: wave-half row max ----
        float pm[2][4];
        #pragma unroll
        for (int qb = 0; qb < 2; ++qb)
            #pragma unroll
            for (int i = 0; i < 4; ++i)
                pm[qb][i] = fmaxf(sc[qb][0][i], sc[qb][1][i]);
        #pragma unroll
        for (int off = 1; off < 16; off <<= 1)
            #pragma unroll
            for (int qb = 0; qb < 2; ++qb)
                #pragma unroll
                for (int i = 0; i < 4; ++i)
                    pm[qb][i] = fmaxf(pm[qb][i], __shfl_xor(pm[qb][i], off));
        if (l15 == 0) {
            float* mh = kh ? mh1 : mh0;
            #pragma unroll
            for (int qb = 0; qb < 2; ++qb)
                #pragma unroll
                for (int i = 0; i < 4; ++i)
                    mh[qh * 32 + qb * 16 + h4 * 4 + i] = pm[qb][i];
        }
        __syncthreads();                          // mhalf visible

        // ---- softmax part 2: exp, sums, P, frow ----
        float f[2][4], lsum[2][4], p[2][2][4];
        #pragma unroll
        for (int qb = 0; qb < 2; ++qb)
            #pragma unroll
            for (int i = 0; i < 4; ++i) {
                const int r = qh * 32 + qb * 16 + h4 * 4 + i;
                const float mnew = fmaxf(m_run[qb][i], fmaxf(mh0[r], mh1[r]));
                f[qb][i] = __expf(m_run[qb][i] - mnew);
                m_run[qb][i] = mnew;
                p[qb][0][i] = __expf(sc[qb][0][i] - mnew);
                p[qb][1][i] = __expf(sc[qb][1][i] - mnew);
                float ls = p[qb][0][i] + p[qb][1][i];
                #pragma unroll
                for (int off = 1; off < 16; off <<= 1) ls += __shfl_xor(ls, off);
                lsum[qb][i] = ls;
            }
        if (l15 == 0) {
            float* lh = kh ? lh1 : lh0;
            #pragma unroll
            for (int qb = 0; qb < 2; ++qb)
                #pragma unroll
                for (int i = 0; i < 4; ++i)
                    lh[qh * 32 + qb * 16 + h4 * 4 + i] = lsum[qb][i];
            if (kh == 0)
                #pragma unroll
                for (int qb = 0; qb < 2; ++qb)
                    #pragma unroll
                    for (int i = 0; i < 4; ++i)
                        frow[qh * 32 + qb * 16 + h4 * 4 + i] = f[qb][i];
        }
        // P store: [q][k] layout, 16 scalar u16 stores
        #pragma unroll
        for (int qb = 0; qb < 2; ++qb)
            #pragma unroll
            for (int kcb = 0; kcb < 2; ++kcb) {
                const int kk = kh * 32 + kcb * 16 + l15;
                #pragma unroll
                for (int i = 0; i < 4; ++i)
                    Pb[(qh * 32 + qb * 16 + h4 * 4 + i) * KP + kk] =
                        f2bf(p[qb][kcb][i]);
            }
        __syncthreads();                          // P, frow, lhalf visible

        {   // running denominator
            const float* lhx = kh ? lh0 : lh1;
            #pragma unroll
            for (int qb = 0; qb < 2; ++qb)
                #pragma unroll
                for (int i = 0; i < 4; ++i) {
                    const int r = qh * 32 + qb * 16 + h4 * 4 + i;
                    l_run[qb][i] = l_run[qb][i] * f[qb][i] + lsum[qb][i] + lhx[r];
                }
        }

        // ---- PV: o^T += V^T * P^T (P fragments = single b128 reads) ----
        float fq[2];
        #pragma unroll
        for (int qb = 0; qb < 2; ++qb) fq[qb] = frow[qh * 32 + qb * 16 + l15];
        #pragma unroll
        for (int db = 0; db < 2; ++db)
            #pragma unroll
            for (int qb = 0; qb < 2; ++qb)
                oacc[db][qb] *= fq[qb];
        __builtin_amdgcn_s_setprio(1);
        #pragma unroll
        for (int kc = 0; kc < 2; ++kc) {
            short8b vf[2], pf[2];
            #pragma unroll
            for (int db = 0; db < 2; ++db)
                vf[db] = *(const short8b*)&Vt[(kh * 32 + db * 16 + l15) * KP + kc * 32 + h4 * 8];
            #pragma unroll
            for (int qb = 0; qb < 2; ++qb)
                pf[qb] = *(const short8b*)&Pb[(qh * 32 + qb * 16 + l15) * KP + kc * 32 + h4 * 8];
            #pragma unroll
            for (int db = 0; db < 2; ++db)
                #pragma unroll
                for (int qb = 0; qb < 2; ++qb)
                    oacc[db][qb] = __builtin_amdgcn_mfma_f32_16x16x32_bf16(
                        vf[db], pf[qb], oacc[db][qb], 0, 0, 0);
        }
        __builtin_amdgcn_s_setprio(0);
        __syncthreads();                          // PV done, buffers free
    }

    float* ob = (sp == 0) ? op0 : ((sp == 1) ? op1 : ((sp == 2) ? op2 : op3));
    #pragma unroll
    for (int db = 0; db < 2; ++db)
        #pragma unroll
        for (int qb = 0; qb < 2; ++qb) {
            const int qq = q0 + qh * 32 + qb * 16 + l15;
            const int d0 = h * DH + kh * 32 + db * 16 + h4 * 4;
            *(f32x4*)&ob[(size_t)qq * DIM + d0] = oacc[db][qb];
        }
    if (kh == 0 && l15 == 0) {
        #pragma unroll
        for (int qb = 0; qb < 2; ++qb)
            #pragma unroll
            for (int i = 0; i < 4; ++i) {
                const int r = qh * 32 + qb * 16 + h4 * 4 + i;
                mpart[((size_t)sp * NN + q0 + r) * NH + h] = m_run[qb][i];
                lpart[((size_t)sp * NN + q0 + r) * NH + h] = l_run[qb][i];
            }
    }
}

// merge the 4 partials (in-place into o0 is safe: thread-private float4s)
__global__ __launch_bounds__(256) void attn_combine(
    const float* o0, const float* __restrict__ o1,
    const float* __restrict__ o2, const float* __restrict__ o3,
    const float* __restrict__ mp, const float* __restrict__ lp,
    float* out)
{
    const int gid = blockIdx.x * 256 + threadIdx.x;
    const int row = gid >> 6;
    const int c4  = (gid & 63) * 4;
    const int h   = c4 >> 6;
    float m[4], wgt[4];
    #pragma unroll
    for (int z = 0; z < 4; ++z) m[z] = mp[((size_t)z * NN + row) * NH + h];
    const float M = fmaxf(fmaxf(m[0], m[1]), fmaxf(m[2], m[3]));
    float den = 0.f;
    #pragma unroll
    for (int z = 0; z < 4; ++z) {
        wgt[z] = __expf(m[z] - M);
        den += lp[((size_t)z * NN + row) * NH + h] * wgt[z];
    }
    const float inv = 1.f / den;
    const float4 a = *(const float4*)&o0[(size_t)row * DIM + c4];
    const float4 b = *(const float4*)&o1[(size_t)row * DIM + c4];
    const float4 c = *(const float4*)&o2[(size_t)row * DIM + c4];
    const float4 d = *(const float4*)&o3[(size_t)row * DIM + c4];
    float4 r;
    r.x = (a.x * wgt[0] + b.x * wgt[1] + c.x * wgt[2] + d.x * wgt[3]) * inv;
    r.y = (a.y * wgt[0] + b.y * wgt[1] + c.y * wgt[2] + d.y * wgt[3]) * inv;
    r.z = (a.z * wgt[0] + b.z * wgt[1] + c.z * wgt[2] + d.z * wgt[3]) * inv;
    r.w = (a.w * wgt[0] + b.w * wgt[1] + c.w * wgt[2] + d.w * wgt[3]) * inv;
    *(float4*)&out[(size_t)row * DIM + c4] = r;
}

// ---------------- per-node group adapter ----------------
__global__ __launch_bounds__(64) void adapter_kernel(
    const float* __restrict__ feats, const int* __restrict__ grp,
    const float* __restrict__ AW1, const float* __restrict__ Ab1,
    const float* __restrict__ AW2, const float* __restrict__ Ab2,
    float* __restrict__ out)
{
    const int n = blockIdx.x;
    const int lane = threadIdx.x;
    __shared__ float f[F1D];
    f[lane]      = feats[(size_t)n * F1D + lane];
    f[lane + 64] = feats[(size_t)n * F1D + 64 + lane];
    __syncthreads();
    const int g = grp[n];
    const float* W1 = AW1 + (size_t)g * F1D * AD;
    const int a = lane & 31;
    const int half = lane >> 5;
    float hsum = 0.f;
    for (int d = 0; d < 64; ++d)
        hsum = fmaf(f[half * 64 + d], W1[(half * 64 + d) * AD + a], hsum);
    hsum += __shfl_xor(hsum, 32);
    hsum = fmaxf(hsum + Ab1[g * AD + a], 0.f);
    float p = hsum * AW2[g * AD + a];
    #pragma unroll
    for (int mm = 1; mm < 32; mm <<= 1) p += __shfl_xor(p, mm);
    if (lane == 0) out[n] = p + Ab2[g];
}

// ---------------- host-side orchestration ----------------
extern "C" void kernel_launch(void* const* d_in, const int* in_sizes, int n_in,
                              void* d_out, int out_size, void* d_ws, size_t ws_size,
                              hipStream_t stream)
{
    const float* x_in   = (const float*)d_in[0];
    const float* eattr  = (const float*)d_in[1];
    const float* Wself  = (const float*)d_in[2];
    const float* Wnbr   = (const float*)d_in[3];
    const float* convb  = (const float*)d_in[4];
    const float* gamma  = (const float*)d_in[5];
    const float* beta   = (const float*)d_in[6];
    const float* bnmean = (const float*)d_in[7];
    const float* bnvar  = (const float*)d_in[8];
    const float* Wqkv   = (const float*)d_in[9];
    const float* bqkv   = (const float*)d_in[10];
    const float* Wo     = (const float*)d_in[11];
    const float* bo     = (const float*)d_in[12];
    const float* fc1W   = (const float*)d_in[13];
    const float* fc1b   = (const float*)d_in[14];
    const float* AW1    = (const float*)d_in[15];
    const float* Ab1    = (const float*)d_in[16];
    const float* AW2    = (const float*)d_in[17];
    const float* Ab2    = (const float*)d_in[18];
    const int*   eidx   = (const int*)d_in[19];
    const int*   grp    = (const int*)d_in[20];
    const int* srcArr = eidx;
    const int* dstArr = eidx + NE;

    float* fws = (float*)d_ws;
    const size_t NM = (size_t)NN * DIM;
    float* bufA  = fws;                  // conv x / residual
    float* bufB  = fws + NM;             // agg / attn op0 / combined o
    float* bufC  = fws + 2 * NM;         // x L1 / op1 / pbuf_wo lo
    float* bufD  = fws + 3 * NM;         // op2 / pbuf head
    float* bufE  = fws + 4 * NM;         // op3 / Wo out
    float* feats = fws + 5 * NM;         // NN x F1D
    float* mpart = fws + 5 * NM + NM / 2;         // [4][NN][NH]
    float* lpart = mpart + 4 * NN * NH;
    u16* qhi = (u16*)(lpart + 4 * NN * NH);       // NN*DIM u16 each
    u16* qlo = qhi + NM;
    u16* khi = qlo + NM;
    u16* klo = khi + NM;
    u16* vt  = klo + NM;                          // [DIM][NN]
    int*   esrc = (int*)(vt + NM);                // NE
    float* ewt  = (float*)(esrc + NE);            // NE
    int* off    = (int*)(ewt + NE);               // NN+1
    int* cur    = off + NN + 1;                   // NN
    float* outp = (float*)d_out;

    float* pbufConv = bufD;              // 4*NM floats (bufD..bf16 arena head, dead here)
    float* pbufWo   = bufC;              // 2*NM floats (bufC+bufD)
    float* pbufFc1  = bufC;              // 4 * NN * F1D = 2*NM floats

    // CSR build
    hipMemsetAsync(cur, 0, NN * sizeof(int), stream);
    csr_count<<<NE / 256, 256, 0, stream>>>(dstArr, cur);
    csr_scan<<<1, 64, 0, stream>>>(cur, off);
    hipMemsetAsync(cur, 0, NN * sizeof(int), stream);
    csr_fill<<<NE / 256, 256, 0, stream>>>(dstArr, srcArr, eattr, off, cur, esrc, ewt);

    const dim3 ggc(DIM / 64, NN / 64, 4);     // conv split-K grid (1024 blocks)
    const int rgrid = NN * DIM / 4 / 256;     // reduce grid for M=256

    // conv layer 0: x_in -> bufA
    agg_kernel<false><<<NN / 4, 256, 0, stream>>>(x_in, esrc, ewt, off, bufB);
    gemm_splitk<true><<<ggc, 256, 0, stream>>>(
        x_in, Wself, bufB, Wnbr, pbufConv, DIM, DIM, 8);
    reduce_epi<EPI_BNELU, 4><<<rgrid, 256, 0, stream>>>(
        pbufConv, convb, gamma, beta, bnmean, bnvar, nullptr, bufA, DIM);
    // conv layer 1: bufA -> bufC
    agg_kernel<false><<<NN / 4, 256, 0, stream>>>(bufA, esrc, ewt, off, bufB);
    gemm_splitk<true><<<ggc, 256, 0, stream>>>(
        bufA, Wself + DIM * DIM, bufB, Wnbr + DIM * DIM, pbufConv, DIM, DIM, 8);
    reduce_epi<EPI_BNELU, 4><<<rgrid, 256, 0, stream>>>(
        pbufConv, convb + DIM, gamma + DIM, beta + DIM, bnmean + DIM, bnvar + DIM,
        nullptr, bufC, DIM);
    // conv layer 2 (edge-weighted): bufC -> bufA
    agg_kernel<true><<<NN / 4, 256, 0, stream>>>(bufC, esrc, ewt, off, bufB);
    gemm_splitk<true><<<ggc, 256, 0, stream>>>(
        bufC, Wself + 2 * DIM * DIM, bufB, Wnbr + 2 * DIM * DIM, pbufConv, DIM, DIM, 8);
    reduce_epi<EPI_BIAS, 4><<<rgrid, 256, 0, stream>>>(
        pbufConv, convb + 2 * DIM, nullptr, nullptr, nullptr, nullptr,
        nullptr, bufA, DIM);

    // fused QKV projection -> bf16 hi/lo Q,K + V^T
    gemm_qkv<<<dim3(3 * DIM / 64, NN / 64), 256, 0, stream>>>(
        bufA, Wqkv, bqkv, qhi, qlo, khi, klo, vt);

    // MFMA flash attention (4-way key split) -> partials, combine -> bufB
    attn_kernel<<<dim3(NN / QB, NH, NSPLIT), 256, 0, stream>>>(
        qhi, qlo, khi, klo, vt, bufB, bufC, bufD, bufE, mpart, lpart);
    attn_combine<<<rgrid, 256, 0, stream>>>(
        bufB, bufC, bufD, bufE, mpart, lpart, bufB);

    // output projection + residual: bufE = bufA + bufB @ Wo + bo
    gemm_splitk<false><<<dim3(DIM / 64, NN / 64, 2), 256, 0, stream>>>(
        bufB, Wo, nullptr, nullptr, pbufWo, DIM, DIM, 8);
    reduce_epi<EPI_BIAS_RES, 2><<<rgrid, 256, 0, stream>>>(
        pbufWo, bo, nullptr, nullptr, nullptr, nullptr, bufA, bufE, DIM);

    // fc1 + ELU: feats = elu(bufE @ fc1W + fc1b)
    gemm_splitk<false><<<dim3(F1D / 64, NN / 64, 4), 256, 0, stream>>>(
        bufE, fc1W, nullptr, nullptr, pbufFc1, DIM, F1D, 4);
    reduce_epi<EPI_BIAS_ELU, 4><<<NN * F1D / 4 / 256, 256, 0, stream>>>(
        pbufFc1, fc1b, nullptr, nullptr, nullptr, nullptr, nullptr, feats, F1D);

    // adapter routing -> out
    adapter_kernel<<<NN, 64, 0, stream>>>(feats, grp, AW1, Ab1, AW2, Ab2, outp);
}

// Round 7
// 329.356 us; speedup vs baseline: 1.2372x; 1.2372x over previous
//
#include <hip/hip_runtime.h>
#include <math.h>

#define NN   4096
#define DIM  256
#define NE   131072
#define NH   4
#define DH   64
#define F1D  128
#define NG   16
#define AD   32

typedef unsigned short u16;
typedef unsigned int   u32;
typedef __attribute__((ext_vector_type(8))) short short8b;
typedef __attribute__((ext_vector_type(4))) float f32x4;

enum { EPI_BIAS = 0, EPI_BNELU = 1, EPI_BIAS_ELU = 2, EPI_BIAS_RES = 3 };

__device__ inline u16 f2bf(float x) {
    u32 u = __float_as_uint(x);
    u += 0x7fffu + ((u >> 16) & 1u);
    return (u16)(u >> 16);
}
__device__ inline float bf2f(u16 h) {
    return __uint_as_float(((u32)h) << 16);
}
__device__ inline u32 packbf(float a, float b) {
    return (u32)f2bf(a) | ((u32)f2bf(b) << 16);
}

// ---------------- CSR build ----------------
__global__ void csr_count(const int* __restrict__ dst, int* __restrict__ cnt) {
    int e = blockIdx.x * 256 + threadIdx.x;
    atomicAdd(&cnt[dst[e]], 1);
}

__global__ void csr_scan(const int* __restrict__ cnt, int* __restrict__ off) {
    int lane = threadIdx.x;
    int base = lane * (NN / 64);
    int s = 0;
    for (int i = 0; i < NN / 64; ++i) s += cnt[base + i];
    int acc = s;
    #pragma unroll
    for (int o = 1; o < 64; o <<= 1) {
        int t = __shfl_up(acc, o);
        if (lane >= o) acc += t;
    }
    int run = acc - s;
    for (int i = 0; i < NN / 64; ++i) { off[base + i] = run; run += cnt[base + i]; }
    if (lane == 63) off[NN] = run;
}

__global__ void csr_fill(const int* __restrict__ dst, const int* __restrict__ src,
                         const float* __restrict__ eattr, const int* __restrict__ off,
                         int* __restrict__ cur, int* __restrict__ esrc,
                         float* __restrict__ ewt) {
    int e = blockIdx.x * 256 + threadIdx.x;
    int d = dst[e];
    int pos = off[d] + atomicAdd(&cur[d], 1);
    esrc[pos] = src[e];
    ewt[pos]  = eattr[e];
}

// ---------------- neighbor aggregation: 1 wave per node -------------------
template<bool LAST>
__global__ __launch_bounds__(256) void agg_kernel(
    const float* __restrict__ x, const int* __restrict__ esrc,
    const float* __restrict__ ewt, const int* __restrict__ off,
    float* __restrict__ agg)
{
    const int node = blockIdx.x * 4 + (threadIdx.x >> 6);
    const int lane = threadIdx.x & 63;
    const int d4 = lane * 4;
    int j = off[node];
    const int j1 = off[node + 1];
    float4 acc = make_float4(0.f, 0.f, 0.f, 0.f);
    for (; j + 4 <= j1; j += 4) {
        const int s0 = esrc[j], s1 = esrc[j + 1], s2 = esrc[j + 2], s3 = esrc[j + 3];
        const float4 x0 = *(const float4*)&x[(size_t)s0 * DIM + d4];
        const float4 x1 = *(const float4*)&x[(size_t)s1 * DIM + d4];
        const float4 x2 = *(const float4*)&x[(size_t)s2 * DIM + d4];
        const float4 x3 = *(const float4*)&x[(size_t)s3 * DIM + d4];
        const float w0 = LAST ? ewt[j]     : 1.f;
        const float w1 = LAST ? ewt[j + 1] : 1.f;
        const float w2 = LAST ? ewt[j + 2] : 1.f;
        const float w3 = LAST ? ewt[j + 3] : 1.f;
        acc.x = fmaf(x0.x, w0, acc.x); acc.y = fmaf(x0.y, w0, acc.y);
        acc.z = fmaf(x0.z, w0, acc.z); acc.w = fmaf(x0.w, w0, acc.w);
        acc.x = fmaf(x1.x, w1, acc.x); acc.y = fmaf(x1.y, w1, acc.y);
        acc.z = fmaf(x1.z, w1, acc.z); acc.w = fmaf(x1.w, w1, acc.w);
        acc.x = fmaf(x2.x, w2, acc.x); acc.y = fmaf(x2.y, w2, acc.y);
        acc.z = fmaf(x2.z, w2, acc.z); acc.w = fmaf(x2.w, w2, acc.w);
        acc.x = fmaf(x3.x, w3, acc.x); acc.y = fmaf(x3.y, w3, acc.y);
        acc.z = fmaf(x3.z, w3, acc.z); acc.w = fmaf(x3.w, w3, acc.w);
    }
    for (; j < j1; ++j) {
        const int s = esrc[j];
        const float w = LAST ? ewt[j] : 1.f;
        const float4 xv = *(const float4*)&x[(size_t)s * DIM + d4];
        acc.x = fmaf(xv.x, w, acc.x); acc.y = fmaf(xv.y, w, acc.y);
        acc.z = fmaf(xv.z, w, acc.z); acc.w = fmaf(xv.w, w, acc.w);
    }
    *(float4*)&agg[(size_t)node * DIM + d4] = acc;
}

// ---------------- fp32 tiled GEMM, 64x64 tile, BK=16, register prefetch ---
template<int EPI, bool DUAL>
__global__ __launch_bounds__(256) void gemm_kernel(
    const float* __restrict__ A0, const float* __restrict__ B0,
    const float* __restrict__ A1, const float* __restrict__ B1,
    const float* __restrict__ bias,
    const float* __restrict__ gamma, const float* __restrict__ beta,
    const float* __restrict__ bnmean, const float* __restrict__ bnvar,
    const float* __restrict__ resid,
    float* __restrict__ out, int K, int M)
{
    __shared__ float As[16][68];
    __shared__ float Bs[16][64];

    const int tid  = threadIdx.x;
    const int row0 = blockIdx.y * 64;
    const int col0 = blockIdx.x * 64;

    const int ty = tid >> 4;
    const int tx = tid & 15;
    const int lrow = tid >> 2;
    const int lk4  = (tid & 3) * 4;
    const int bk   = tid >> 4;
    const int bc4  = (tid & 15) * 4;

    float acc[4][4] = {};
    const int kTot = DUAL ? 2 * K : K;

    float4 av, bv;
    av = *(const float4*)&A0[(size_t)(row0 + lrow) * K + lk4];
    bv = *(const float4*)&B0[(size_t)bk * M + col0 + bc4];
    for (int k0 = 0; k0 < kTot; k0 += 16) {
        __syncthreads();
        As[lk4 + 0][lrow] = av.x;
        As[lk4 + 1][lrow] = av.y;
        As[lk4 + 2][lrow] = av.z;
        As[lk4 + 3][lrow] = av.w;
        *(float4*)&Bs[bk][bc4] = bv;
        if (k0 + 16 < kTot) {
            const int kn = k0 + 16;
            const bool ph1 = DUAL && (kn >= K);
            const float* A = ph1 ? A1 : A0;
            const float* B = ph1 ? B1 : B0;
            const int kb = ph1 ? (kn - K) : kn;
            av = *(const float4*)&A[(size_t)(row0 + lrow) * K + kb + lk4];
            bv = *(const float4*)&B[(size_t)(kb + bk) * M + col0 + bc4];
        }
        __syncthreads();
        #pragma unroll
        for (int kk = 0; kk < 16; ++kk) {
            float4 a = *(const float4*)&As[kk][ty * 4];
            float4 b = *(const float4*)&Bs[kk][tx * 4];
            acc[0][0] = fmaf(a.x, b.x, acc[0][0]);
            acc[0][1] = fmaf(a.x, b.y, acc[0][1]);
            acc[0][2] = fmaf(a.x, b.z, acc[0][2]);
            acc[0][3] = fmaf(a.x, b.w, acc[0][3]);
            acc[1][0] = fmaf(a.y, b.x, acc[1][0]);
            acc[1][1] = fmaf(a.y, b.y, acc[1][1]);
            acc[1][2] = fmaf(a.y, b.z, acc[1][2]);
            acc[1][3] = fmaf(a.y, b.w, acc[1][3]);
            acc[2][0] = fmaf(a.z, b.x, acc[2][0]);
            acc[2][1] = fmaf(a.z, b.y, acc[2][1]);
            acc[2][2] = fmaf(a.z, b.z, acc[2][2]);
            acc[2][3] = fmaf(a.z, b.w, acc[2][3]);
            acc[3][0] = fmaf(a.w, b.x, acc[3][0]);
            acc[3][1] = fmaf(a.w, b.y, acc[3][1]);
            acc[3][2] = fmaf(a.w, b.z, acc[3][2]);
            acc[3][3] = fmaf(a.w, b.w, acc[3][3]);
        }
    }
    #pragma unroll
    for (int i = 0; i < 4; ++i) {
        const int r = row0 + ty * 4 + i;
        #pragma unroll
        for (int j = 0; j < 4; ++j) {
            const int c = col0 + tx * 4 + j;
            float v = acc[i][j] + bias[c];
            if (EPI == EPI_BNELU) {
                v = gamma[c] * (v - bnmean[c]) * rsqrtf(bnvar[c] + 1e-5f) + beta[c];
                v = v > 0.f ? v : expm1f(v);
            } else if (EPI == EPI_BIAS_ELU) {
                v = v > 0.f ? v : expm1f(v);
            } else if (EPI == EPI_BIAS_RES) {
                v += resid[(size_t)r * M + c];
            }
            out[(size_t)r * M + c] = v;
        }
    }
}

// ---------------- fused QKV GEMM (single launch, bf16 hi/lo epilogue) -----
__global__ __launch_bounds__(256) void gemm_qkv(
    const float* __restrict__ A0, const float* __restrict__ B0,
    const float* __restrict__ bias,
    u16* __restrict__ qh_o, u16* __restrict__ ql_o,
    u16* __restrict__ kh_o, u16* __restrict__ kl_o,
    u16* __restrict__ vt_o)
{
    __shared__ float As[16][68];
    __shared__ float Bs[16][64];
    const int K = DIM, M = DIM;

    const int tid  = threadIdx.x;
    const int row0 = blockIdx.y * 64;
    const int c0raw = blockIdx.x * 64;
    const int mat  = c0raw >> 8;
    const int col0 = c0raw & 255;
    const float* Bp = B0 + (size_t)mat * K * M;
    const float* biasp = bias + mat * M;

    const int ty = tid >> 4;
    const int tx = tid & 15;
    const int lrow = tid >> 2;
    const int lk4  = (tid & 3) * 4;
    const int bk   = tid >> 4;
    const int bc4  = (tid & 15) * 4;

    float acc[4][4] = {};
    float4 av, bv;
    av = *(const float4*)&A0[(size_t)(row0 + lrow) * K + lk4];
    bv = *(const float4*)&Bp[(size_t)bk * M + col0 + bc4];
    for (int k0 = 0; k0 < K; k0 += 16) {
        __syncthreads();
        As[lk4 + 0][lrow] = av.x;
        As[lk4 + 1][lrow] = av.y;
        As[lk4 + 2][lrow] = av.z;
        As[lk4 + 3][lrow] = av.w;
        *(float4*)&Bs[bk][bc4] = bv;
        if (k0 + 16 < K) {
            const int kb = k0 + 16;
            av = *(const float4*)&A0[(size_t)(row0 + lrow) * K + kb + lk4];
            bv = *(const float4*)&Bp[(size_t)(kb + bk) * M + col0 + bc4];
        }
        __syncthreads();
        #pragma unroll
        for (int kk = 0; kk < 16; ++kk) {
            float4 a = *(const float4*)&As[kk][ty * 4];
            float4 b = *(const float4*)&Bs[kk][tx * 4];
            acc[0][0] = fmaf(a.x, b.x, acc[0][0]);
            acc[0][1] = fmaf(a.x, b.y, acc[0][1]);
            acc[0][2] = fmaf(a.x, b.z, acc[0][2]);
            acc[0][3] = fmaf(a.x, b.w, acc[0][3]);
            acc[1][0] = fmaf(a.y, b.x, acc[1][0]);
            acc[1][1] = fmaf(a.y, b.y, acc[1][1]);
            acc[1][2] = fmaf(a.y, b.z, acc[1][2]);
            acc[1][3] = fmaf(a.y, b.w, acc[1][3]);
            acc[2][0] = fmaf(a.z, b.x, acc[2][0]);
            acc[2][1] = fmaf(a.z, b.y, acc[2][1]);
            acc[2][2] = fmaf(a.z, b.z, acc[2][2]);
            acc[2][3] = fmaf(a.z, b.w, acc[2][3]);
            acc[3][0] = fmaf(a.w, b.x, acc[3][0]);
            acc[3][1] = fmaf(a.w, b.y, acc[3][1]);
            acc[3][2] = fmaf(a.w, b.z, acc[3][2]);
            acc[3][3] = fmaf(a.w, b.w, acc[3][3]);
        }
    }
    if (mat < 2) {
        const float s = (mat == 0) ? 0.125f : 1.0f;
        u16* hi = (mat == 0) ? qh_o : kh_o;
        u16* lo = (mat == 0) ? ql_o : kl_o;
        #pragma unroll
        for (int i = 0; i < 4; ++i) {
            const int r = row0 + ty * 4 + i;
            const int c = col0 + tx * 4;
            u32 wh[2], wl[2];
            #pragma unroll
            for (int g = 0; g < 2; ++g) {
                float v0 = (acc[i][g * 2]     + biasp[c + g * 2])     * s;
                float v1 = (acc[i][g * 2 + 1] + biasp[c + g * 2 + 1]) * s;
                u16 h0 = f2bf(v0), h1 = f2bf(v1);
                float l0 = v0 - bf2f(h0), l1 = v1 - bf2f(h1);
                wh[g] = (u32)h0 | ((u32)h1 << 16);
                wl[g] = packbf(l0, l1);
            }
            *(uint2*)&hi[(size_t)r * DIM + c] = make_uint2(wh[0], wh[1]);
            *(uint2*)&lo[(size_t)r * DIM + c] = make_uint2(wl[0], wl[1]);
        }
    } else {
        #pragma unroll
        for (int j = 0; j < 4; ++j) {
            const int c = col0 + tx * 4 + j;
            const int r = row0 + ty * 4;
            float v0 = acc[0][j] + biasp[c];
            float v1 = acc[1][j] + biasp[c];
            float v2 = acc[2][j] + biasp[c];
            float v3 = acc[3][j] + biasp[c];
            *(uint2*)&vt_o[(size_t)c * NN + r] =
                make_uint2(packbf(v0, v1), packbf(v2, v3));
        }
    }
}

// ---------------- MFMA flash attention -----------------------------------
// 64x64 tiles; QK^T fp32-emulated via bf16 hi/lo (4 mfma passes); PV bf16.
// P stored [q][k] (stride 72 u16) so PV B-fragments are single ds_read_b128.
// LDS 38144 B fits 4 blocks/CU; launch_bounds min=3 (VGPR ~80, no spill —
// round-6 lesson: min=4 squeezed VGPR to 64 and spilled 400+MB to scratch).
#define QB 64
#define KB 64
#define NSPLIT 4
#define NKT (NN / KB)
#define KP 72

__global__ __launch_bounds__(256, 3) void attn_kernel(
    const u16* __restrict__ qhi, const u16* __restrict__ qlo,
    const u16* __restrict__ khi, const u16* __restrict__ klo,
    const u16* __restrict__ vT,
    float* __restrict__ op0, float* __restrict__ op1,
    float* __restrict__ op2, float* __restrict__ op3,
    float* __restrict__ mpart, float* __restrict__ lpart)
{
    __shared__ u16 lds[19072];            // 38144 B
    u16* Kh = lds;                        // [64][72]
    u16* Kl = lds + 4608;
    u16* Vt = lds + 9216;                 // [key][d] per-head
    u16* Pb = lds + 13824;                // [q][72]  P bf16
    u16* Qh = lds;                        // overlay: init phase only
    u16* Ql = lds + 4608;                 // overlay: init phase only
    float* fls = (float*)(lds + 18432);   // 320 floats
    float* mh0 = fls;
    float* mh1 = fls + 64;
    float* lh0 = fls + 128;
    float* lh1 = fls + 192;
    float* frow = fls + 256;

    const int tid = threadIdx.x;
    const int h   = blockIdx.y;
    const int q0  = blockIdx.x * QB;
    const int sp  = blockIdx.z;
    const int kt0 = (sp * NKT) / NSPLIT;
    const int kt1 = ((sp + 1) * NKT) / NSPLIT;

    const int w   = tid >> 6;
    const int l   = tid & 63;
    const int l15 = l & 15, h4 = l >> 4;
    const int qh  = w & 1, kh = w >> 1;

    const int lrow = tid & 63, lseg = tid >> 6;
    const int gq = h * DH + lseg * 16;

    {   // stage Q (once, into overlay region)
        const u16* s0 = qhi + (size_t)(q0 + lrow) * DIM + gq;
        const u16* s1 = qlo + (size_t)(q0 + lrow) * DIM + gq;
        uint4 a = ((const uint4*)s0)[0], b = ((const uint4*)s0)[1];
        uint4 c = ((const uint4*)s1)[0], d = ((const uint4*)s1)[1];
        *(uint4*)&Qh[lrow * KP + lseg * 16]     = a;
        *(uint4*)&Qh[lrow * KP + lseg * 16 + 8] = b;
        *(uint4*)&Ql[lrow * KP + lseg * 16]     = c;
        *(uint4*)&Ql[lrow * KP + lseg * 16 + 8] = d;
    }
    uint4 ska, skb, sla, slb, sva, svb;
    {
        const int key0 = kt0 * KB;
        const u16* s0 = khi + (size_t)(key0 + lrow) * DIM + gq;
        const u16* s1 = klo + (size_t)(key0 + lrow) * DIM + gq;
        const u16* s2 = vT + (size_t)(h * DH + lrow) * NN + key0 + lseg * 16;
        ska = ((const uint4*)s0)[0]; skb = ((const uint4*)s0)[1];
        sla = ((const uint4*)s1)[0]; slb = ((const uint4*)s1)[1];
        sva = ((const uint4*)s2)[0]; svb = ((const uint4*)s2)[1];
    }
    __syncthreads();                              // Q staged

    short8b qf[2][2][2];
    #pragma unroll
    for (int qb = 0; qb < 2; ++qb)
        #pragma unroll
        for (int kc = 0; kc < 2; ++kc) {
            const int r = qh * 32 + qb * 16 + l15;
            const int dc = kc * 32 + h4 * 8;
            qf[qb][kc][0] = *(const short8b*)&Qh[r * KP + dc];
            qf[qb][kc][1] = *(const short8b*)&Ql[r * KP + dc];
        }
    __syncthreads();                              // hoist done; overlay safe

    const f32x4 z4 = {0.f, 0.f, 0.f, 0.f};
    f32x4 oacc[2][2] = {{z4, z4}, {z4, z4}};
    float m_run[2][4], l_run[2][4];
    #pragma unroll
    for (int qb = 0; qb < 2; ++qb)
        #pragma unroll
        for (int i = 0; i < 4; ++i) { m_run[qb][i] = -3.0e38f; l_run[qb][i] = 0.f; }

    for (int kt = kt0; kt < kt1; ++kt) {
        *(uint4*)&Kh[lrow * KP + lseg * 16]     = ska;
        *(uint4*)&Kh[lrow * KP + lseg * 16 + 8] = skb;
        *(uint4*)&Kl[lrow * KP + lseg * 16]     = sla;
        *(uint4*)&Kl[lrow * KP + lseg * 16 + 8] = slb;
        *(uint4*)&Vt[lrow * KP + lseg * 16]     = sva;
        *(uint4*)&Vt[lrow * KP + lseg * 16 + 8] = svb;
        __syncthreads();                          // tile staged

        // ---- S = Q K^T (4-pass hi/lo) ----
        f32x4 sc[2][2] = {{z4, z4}, {z4, z4}};
        __builtin_amdgcn_s_setprio(1);
        #pragma unroll
        for (int kc = 0; kc < 2; ++kc) {
            short8b kfh[2], kfl[2];
            #pragma unroll
            for (int kcb = 0; kcb < 2; ++kcb) {
                const int r = kh * 32 + kcb * 16 + l15;
                const int dc = kc * 32 + h4 * 8;
                kfh[kcb] = *(const short8b*)&Kh[r * KP + dc];
                kfl[kcb] = *(const short8b*)&Kl[r * KP + dc];
            }
            #pragma unroll
            for (int qb = 0; qb < 2; ++qb)
                #pragma unroll
                for (int kcb = 0; kcb < 2; ++kcb) {
                    sc[qb][kcb] = __builtin_amdgcn_mfma_f32_16x16x32_bf16(
                        qf[qb][kc][0], kfh[kcb], sc[qb][kcb], 0, 0, 0);
                    sc[qb][kcb] = __builtin_amdgcn_mfma_f32_16x16x32_bf16(
                        qf[qb][kc][0], kfl[kcb], sc[qb][kcb], 0, 0, 0);
                    sc[qb][kcb] = __builtin_amdgcn_mfma_f32_16x16x32_bf16(
                        qf[qb][kc][1], kfh[kcb], sc[qb][kcb], 0, 0, 0);
                    sc[qb][kcb] = __builtin_amdgcn_mfma_f32_16x16x32_bf16(
                        qf[qb][kc][1], kfl[kcb], sc[qb][kcb], 0, 0, 0);
                }
        }
        __builtin_amdgcn_s_setprio(0);
        // prefetch next tile while softmax runs
        if (kt + 1 < kt1) {
            const int key0 = (kt + 1) * KB;
            const u16* s0 = khi + (size_t)(key0 + lrow) * DIM + gq;
            const u16* s1 = klo + (size_t)(key0 + lrow) * DIM + gq;
            const u16* s2 = vT + (size_t)(h * DH + lrow) * NN + key0 + lseg * 16;
            ska = ((const uint4*)s0)[0]; skb = ((const uint4*)s0)[1];
            sla = ((const uint4*)s1)[0]; slb = ((const uint4*)s1)[1];
            sva = ((const uint4*)s2)[0]; svb = ((const uint4*)s2)[1];
        }
        // ---- softmax part 1: wave-half row max ----
        float pm[2][4];
        #pragma unroll
        for (int qb = 0; qb < 2; ++qb)
            #pragma unroll
            for (int i = 0; i < 4; ++i)
                pm[qb][i] = fmaxf(sc[qb][0][i], sc[qb][1][i]);
        #pragma unroll
        for (int off = 1; off < 16; off <<= 1)
            #pragma unroll
            for (int qb = 0; qb < 2; ++qb)
                #pragma unroll
                for (int i = 0; i < 4; ++i)
                    pm[qb][i] = fmaxf(pm[qb][i], __shfl_xor(pm[qb][i], off));
        if (l15 == 0) {
            float* mh = kh ? mh1 : mh0;
            #pragma unroll
            for (int qb = 0; qb < 2; ++qb)
                #pragma unroll
                for (int i = 0; i < 4; ++i)
                    mh[qh * 32 + qb * 16 + h4 * 4 + i] = pm[qb][i];
        }
        __syncthreads();                          // mhalf visible

        // ---- softmax part 2: exp, sums, P, frow ----
        float f[2][4], lsum[2][4], p[2][2][4];
        #pragma unroll
        for (int qb = 0; qb < 2; ++qb)
            #pragma unroll
            for (int i = 0; i < 4; ++i) {
                const int r = qh * 32 + qb * 16 + h4 * 4 + i;
                const float mnew = fmaxf(m_run[qb][i], fmaxf(mh0[r], mh1[r]));
                f[qb][i] = __expf(m_run[qb][i] - mnew);
                m_run[qb][i] = mnew;
                p[qb][0][i] = __expf(sc[qb][0][i] - mnew);
                p[qb][1][i] = __expf(sc[qb][1][i] - mnew);
                float ls = p[qb][0][i] + p[qb][1][i];
                #pragma unroll
                for (int off = 1; off < 16; off <<= 1) ls += __shfl_xor(ls, off);
                lsum[qb][i] = ls;
            }
        if (l15 == 0) {
            float* lh = kh ? lh1 : lh0;
            #pragma unroll
            for (int qb = 0; qb < 2; ++qb)
                #pragma unroll
                for (int i = 0; i < 4; ++i)
                    lh[qh * 32 + qb * 16 + h4 * 4 + i] = lsum[qb][i];
            if (kh == 0)
                #pragma unroll
                for (int qb = 0; qb < 2; ++qb)
                    #pragma unroll
                    for (int i = 0; i < 4; ++i)
                        frow[qh * 32 + qb * 16 + h4 * 4 + i] = f[qb][i];
        }
        // P store: [q][k] layout, 16 scalar u16 stores
        #pragma unroll
        for (int qb = 0; qb < 2; ++qb)
            #pragma unroll
            for (int kcb = 0; kcb < 2; ++kcb) {
                const int kk = kh * 32 + kcb * 16 + l15;
                #pragma unroll
                for (int i = 0; i < 4; ++i)
                    Pb[(qh * 32 + qb * 16 + h4 * 4 + i) * KP + kk] =
                        f2bf(p[qb][kcb][i]);
            }
        __syncthreads();                          // P, frow, lhalf visible

        {   // running denominator
            const float* lhx = kh ? lh0 : lh1;
            #pragma unroll
            for (int qb = 0; qb < 2; ++qb)
                #pragma unroll
                for (int i = 0; i < 4; ++i) {
                    const int r = qh * 32 + qb * 16 + h4 * 4 + i;
                    l_run[qb][i] = l_run[qb][i] * f[qb][i] + lsum[qb][i] + lhx[r];
                }
        }

        // ---- PV: o^T += V^T * P^T (P fragments = single b128 reads) ----
        float fq[2];
        #pragma unroll
        for (int qb = 0; qb < 2; ++qb) fq[qb] = frow[qh * 32 + qb * 16 + l15];
        #pragma unroll
        for (int db = 0; db < 2; ++db)
            #pragma unroll
            for (int qb = 0; qb < 2; ++qb)
                oacc[db][qb] *= fq[qb];
        __builtin_amdgcn_s_setprio(1);
        #pragma unroll
        for (int kc = 0; kc < 2; ++kc) {
            short8b vf[2], pf[2];
            #pragma unroll
            for (int db = 0; db < 2; ++db)
                vf[db] = *(const short8b*)&Vt[(kh * 32 + db * 16 + l15) * KP + kc * 32 + h4 * 8];
            #pragma unroll
            for (int qb = 0; qb < 2; ++qb)
                pf[qb] = *(const short8b*)&Pb[(qh * 32 + qb * 16 + l15) * KP + kc * 32 + h4 * 8];
            #pragma unroll
            for (int db = 0; db < 2; ++db)
                #pragma unroll
                for (int qb = 0; qb < 2; ++qb)
                    oacc[db][qb] = __builtin_amdgcn_mfma_f32_16x16x32_bf16(
                        vf[db], pf[qb], oacc[db][qb], 0, 0, 0);
        }
        __builtin_amdgcn_s_setprio(0);
        __syncthreads();                          // PV done, buffers free
    }

    float* ob = (sp == 0) ? op0 : ((sp == 1) ? op1 : ((sp == 2) ? op2 : op3));
    #pragma unroll
    for (int db = 0; db < 2; ++db)
        #pragma unroll
        for (int qb = 0; qb < 2; ++qb) {
            const int qq = q0 + qh * 32 + qb * 16 + l15;
            const int d0 = h * DH + kh * 32 + db * 16 + h4 * 4;
            *(f32x4*)&ob[(size_t)qq * DIM + d0] = oacc[db][qb];
        }
    if (kh == 0 && l15 == 0) {
        #pragma unroll
        for (int qb = 0; qb < 2; ++qb)
            #pragma unroll
            for (int i = 0; i < 4; ++i) {
                const int r = qh * 32 + qb * 16 + h4 * 4 + i;
                mpart[((size_t)sp * NN + q0 + r) * NH + h] = m_run[qb][i];
                lpart[((size_t)sp * NN + q0 + r) * NH + h] = l_run[qb][i];
            }
    }
}

// merge the 4 partials (in-place into o0 is safe: thread-private float4s)
__global__ __launch_bounds__(256) void attn_combine(
    const float* o0, const float* __restrict__ o1,
    const float* __restrict__ o2, const float* __restrict__ o3,
    const float* __restrict__ mp, const float* __restrict__ lp,
    float* out)
{
    const int gid = blockIdx.x * 256 + threadIdx.x;
    const int row = gid >> 6;
    const int c4  = (gid & 63) * 4;
    const int h   = c4 >> 6;
    float m[4], wgt[4];
    #pragma unroll
    for (int z = 0; z < 4; ++z) m[z] = mp[((size_t)z * NN + row) * NH + h];
    const float M = fmaxf(fmaxf(m[0], m[1]), fmaxf(m[2], m[3]));
    float den = 0.f;
    #pragma unroll
    for (int z = 0; z < 4; ++z) {
        wgt[z] = __expf(m[z] - M);
        den += lp[((size_t)z * NN + row) * NH + h] * wgt[z];
    }
    const float inv = 1.f / den;
    const float4 a = *(const float4*)&o0[(size_t)row * DIM + c4];
    const float4 b = *(const float4*)&o1[(size_t)row * DIM + c4];
    const float4 c = *(const float4*)&o2[(size_t)row * DIM + c4];
    const float4 d = *(const float4*)&o3[(size_t)row * DIM + c4];
    float4 r;
    r.x = (a.x * wgt[0] + b.x * wgt[1] + c.x * wgt[2] + d.x * wgt[3]) * inv;
    r.y = (a.y * wgt[0] + b.y * wgt[1] + c.y * wgt[2] + d.y * wgt[3]) * inv;
    r.z = (a.z * wgt[0] + b.z * wgt[1] + c.z * wgt[2] + d.z * wgt[3]) * inv;
    r.w = (a.w * wgt[0] + b.w * wgt[1] + c.w * wgt[2] + d.w * wgt[3]) * inv;
    *(float4*)&out[(size_t)row * DIM + c4] = r;
}

// ---------------- per-node group adapter ----------------
__global__ __launch_bounds__(64) void adapter_kernel(
    const float* __restrict__ feats, const int* __restrict__ grp,
    const float* __restrict__ AW1, const float* __restrict__ Ab1,
    const float* __restrict__ AW2, const float* __restrict__ Ab2,
    float* __restrict__ out)
{
    const int n = blockIdx.x;
    const int lane = threadIdx.x;
    __shared__ float f[F1D];
    f[lane]      = feats[(size_t)n * F1D + lane];
    f[lane + 64] = feats[(size_t)n * F1D + 64 + lane];
    __syncthreads();
    const int g = grp[n];
    const float* W1 = AW1 + (size_t)g * F1D * AD;
    const int a = lane & 31;
    const int half = lane >> 5;
    float hsum = 0.f;
    for (int d = 0; d < 64; ++d)
        hsum = fmaf(f[half * 64 + d], W1[(half * 64 + d) * AD + a], hsum);
    hsum += __shfl_xor(hsum, 32);
    hsum = fmaxf(hsum + Ab1[g * AD + a], 0.f);
    float p = hsum * AW2[g * AD + a];
    #pragma unroll
    for (int mm = 1; mm < 32; mm <<= 1) p += __shfl_xor(p, mm);
    if (lane == 0) out[n] = p + Ab2[g];
}

// ---------------- host-side orchestration ----------------
extern "C" void kernel_launch(void* const* d_in, const int* in_sizes, int n_in,
                              void* d_out, int out_size, void* d_ws, size_t ws_size,
                              hipStream_t stream)
{
    const float* x_in   = (const float*)d_in[0];
    const float* eattr  = (const float*)d_in[1];
    const float* Wself  = (const float*)d_in[2];
    const float* Wnbr   = (const float*)d_in[3];
    const float* convb  = (const float*)d_in[4];
    const float* gamma  = (const float*)d_in[5];
    const float* beta   = (const float*)d_in[6];
    const float* bnmean = (const float*)d_in[7];
    const float* bnvar  = (const float*)d_in[8];
    const float* Wqkv   = (const float*)d_in[9];
    const float* bqkv   = (const float*)d_in[10];
    const float* Wo     = (const float*)d_in[11];
    const float* bo     = (const float*)d_in[12];
    const float* fc1W   = (const float*)d_in[13];
    const float* fc1b   = (const float*)d_in[14];
    const float* AW1    = (const float*)d_in[15];
    const float* Ab1    = (const float*)d_in[16];
    const float* AW2    = (const float*)d_in[17];
    const float* Ab2    = (const float*)d_in[18];
    const int*   eidx   = (const int*)d_in[19];
    const int*   grp    = (const int*)d_in[20];
    const int* srcArr = eidx;
    const int* dstArr = eidx + NE;

    float* fws = (float*)d_ws;
    const size_t NM = (size_t)NN * DIM;
    float* bufA  = fws;                  // conv x / residual
    float* bufB  = fws + NM;             // agg / attn op0 / combined o
    float* bufC  = fws + 2 * NM;         // x L1 / op1
    float* bufD  = fws + 3 * NM;         // op2
    float* bufE  = fws + 4 * NM;         // op3 / Wo out
    float* feats = fws + 5 * NM;         // NN x F1D
    float* mpart = fws + 5 * NM + NM / 2;         // [4][NN][NH]
    float* lpart = mpart + 4 * NN * NH;
    u16* qhi = (u16*)(lpart + 4 * NN * NH);       // NN*DIM u16 each
    u16* qlo = qhi + NM;
    u16* khi = qlo + NM;
    u16* klo = khi + NM;
    u16* vt  = klo + NM;                          // [DIM][NN]
    int*   esrc = (int*)(vt + NM);                // NE
    float* ewt  = (float*)(esrc + NE);            // NE
    int* off    = (int*)(ewt + NE);               // NN+1
    int* cur    = off + NN + 1;                   // NN
    float* outp = (float*)d_out;

    // CSR build
    hipMemsetAsync(cur, 0, NN * sizeof(int), stream);
    csr_count<<<NE / 256, 256, 0, stream>>>(dstArr, cur);
    csr_scan<<<1, 64, 0, stream>>>(cur, off);
    hipMemsetAsync(cur, 0, NN * sizeof(int), stream);
    csr_fill<<<NE / 256, 256, 0, stream>>>(dstArr, srcArr, eattr, off, cur, esrc, ewt);

    const dim3 gg(DIM / 64, NN / 64);
    const int rgrid = NN * DIM / 4 / 256;

    // conv layer 0: x_in -> bufA
    agg_kernel<false><<<NN / 4, 256, 0, stream>>>(x_in, esrc, ewt, off, bufB);
    gemm_kernel<EPI_BNELU, true><<<gg, 256, 0, stream>>>(
        x_in, Wself, bufB, Wnbr, convb, gamma, beta, bnmean, bnvar,
        nullptr, bufA, DIM, DIM);
    // conv layer 1: bufA -> bufC
    agg_kernel<false><<<NN / 4, 256, 0, stream>>>(bufA, esrc, ewt, off, bufB);
    gemm_kernel<EPI_BNELU, true><<<gg, 256, 0, stream>>>(
        bufA, Wself + DIM * DIM, bufB, Wnbr + DIM * DIM, convb + DIM,
        gamma + DIM, beta + DIM, bnmean + DIM, bnvar + DIM,
        nullptr, bufC, DIM, DIM);
    // conv layer 2 (edge-weighted): bufC -> bufA
    agg_kernel<true><<<NN / 4, 256, 0, stream>>>(bufC, esrc, ewt, off, bufB);
    gemm_kernel<EPI_BIAS, true><<<gg, 256, 0, stream>>>(
        bufC, Wself + 2 * DIM * DIM, bufB, Wnbr + 2 * DIM * DIM, convb + 2 * DIM,
        nullptr, nullptr, nullptr, nullptr, nullptr, bufA, DIM, DIM);

    // fused QKV projection -> bf16 hi/lo Q,K + V^T
    gemm_qkv<<<dim3(3 * DIM / 64, NN / 64), 256, 0, stream>>>(
        bufA, Wqkv, bqkv, qhi, qlo, khi, klo, vt);

    // MFMA flash attention (4-way key split) -> partials, combine -> bufB
    attn_kernel<<<dim3(NN / QB, NH, NSPLIT), 256, 0, stream>>>(
        qhi, qlo, khi, klo, vt, bufB, bufC, bufD, bufE, mpart, lpart);
    attn_combine<<<rgrid, 256, 0, stream>>>(
        bufB, bufC, bufD, bufE, mpart, lpart, bufB);

    // output projection + residual: bufE = bufA + bufB @ Wo + bo
    gemm_kernel<EPI_BIAS_RES, false><<<gg, 256, 0, stream>>>(
        bufB, Wo, nullptr, nullptr, bo,
        nullptr, nullptr, nullptr, nullptr, bufA, bufE, DIM, DIM);

    // fc1 + ELU: feats = elu(bufE @ fc1W + fc1b)
    gemm_kernel<EPI_BIAS_ELU, false><<<dim3(F1D / 64, NN / 64), 256, 0, stream>>>(
        bufE, fc1W, nullptr, nullptr, fc1b,
        nullptr, nullptr, nullptr, nullptr, nullptr, feats, DIM, F1D);

    // adapter routing -> out
    adapter_kernel<<<NN, 64, 0, stream>>>(feats, grp, AW1, Ab1, AW2, Ab2, outp);
}